// Round 7
// baseline (344.307 us; speedup 1.0000x reference)
//
#include <hip/hip_runtime.h>
#include <stdint.h>

// ---------------------------------------------------------------------------
// DistributedAttention on MI355X (gfx950)
//   q = x Wq^T + bq ; k = x Wk^T + bk ; v = x Wv^T + bv
//   P = softmax(q k^T / 8) ; out = P v Wo^T + bo
// Factorizations:
//   F  = Wo . Wv                  (2.1 GF, replaces the 17.2 GF v-proj)  [R7]
//   Vot= F . x^T per batch        ([H][S] bf16)                          [R7]
//   G  = Wq^T . Wk  (batch-indep) ; qg = x . G + g0, g0 = bq^T Wk        [R11]
//   scores = qg . x^T   (row-constant terms cancel in softmax)           [R12]
//   P_un = exp(scores / 8)        (bf16 + atomic fp32 rowsums)
//   out  = (P_un . Vot^T)/rowsum + bfinal,  bfinal = bo + Wo.bv
// R15: dispatch-count reduction (9 -> 5 graph nodes) to attack the ~75 µs
//   constant residual (total minus summed kernel estimates) that has not
//   moved since R0:
//   - both hipMemsetAsync nodes deleted;
//   - rsum zeroing back inside cvt_all (8 blocks; consumed 2 dispatches
//     later -> no ordering hazard);
//   - g0 computed in gemm_gf (runs after cvt) from the bf16 WkT rows,
//     atomic-free and fully coalesced (lane-per-bf16x8, hoisted bq
//     slices); with bq=0 in the harness inputs g0=0 exactly either way.
//   Kernel variants frozen per A/B history: scores/qgv/gf on the 128^2
//   2-barrier path, final on the 128x256 phase-split path.
// ---------------------------------------------------------------------------

typedef __bf16 bf16x8 __attribute__((ext_vector_type(8)));
typedef float  f32x4  __attribute__((ext_vector_type(4)));

__device__ __forceinline__ unsigned short f32_to_bf16_rne(float f) {
    uint32_t u = __builtin_bit_cast(uint32_t, f);
    uint32_t r = (u + 0x7FFFu + ((u >> 16) & 1u)) >> 16;
    return (unsigned short)r;
}

#define BM 128
#define BN 128
#define BK 64

// ---------------------------------------------------------------------------
// One-dispatch prep, 10008 blocks:
//   [0,8192)        x fp32 -> x16 bf16
//   [8192,9216)     Wo straight convert -> w16 slot 2
//   [9216,9984)     WqT, WkT, WvT 64x64-tile transposes -> slots 0,1,3
//   [9984,10000)    bfinal = bo + Wo.bv
//   [10000,10008)   zero rsum
// ---------------------------------------------------------------------------
__global__ __launch_bounds__(256) void cvt_all(
    const float* __restrict__ x,
    const float* __restrict__ Wq, const float* __restrict__ Wk,
    const float* __restrict__ Wo, const float* __restrict__ Wv,
    const float* __restrict__ bv, const float* __restrict__ bo,
    unsigned short* __restrict__ x16, unsigned short* __restrict__ w16,
    float* __restrict__ rsum, float* __restrict__ bfinal)
{
    const int b = blockIdx.x, tid = threadIdx.x;
    if (b < 8192) {
        int i = (b * 256 + tid) * 4;
        float4 v = *(const float4*)(x + i);
        ushort4 o;
        o.x = f32_to_bf16_rne(v.x); o.y = f32_to_bf16_rne(v.y);
        o.z = f32_to_bf16_rne(v.z); o.w = f32_to_bf16_rne(v.w);
        *(ushort4*)(x16 + i) = o;
    } else if (b < 9216) {
        int i = ((b - 8192) * 256 + tid) * 4;
        float4 v = *(const float4*)(Wo + i);
        ushort4 o;
        o.x = f32_to_bf16_rne(v.x); o.y = f32_to_bf16_rne(v.y);
        o.z = f32_to_bf16_rne(v.z); o.w = f32_to_bf16_rne(v.w);
        *(ushort4*)(w16 + (size_t)2 * 1048576 + i) = o;
    } else if (b < 9984) {
        // transpose one 64x64 tile of {Wq,Wk,Wv} into w16 slot {0,1,3}
        __shared__ unsigned short tl[64 * 68];   // [c][r], stride 68
        int t = b - 9216;
        int which = t >> 8;                      // 0:Wq 1:Wk 2:Wv
        const float* src = which == 0 ? Wq : which == 1 ? Wk : Wv;
        size_t slot = which == 0 ? 0 : which == 1 ? 1 : 3;
        int tile = t & 255, tr = tile >> 4, tc = tile & 15;
        #pragma unroll
        for (int it = 0; it < 4; ++it) {
            int r  = it * 16 + (tid >> 4);
            int c0 = (tid & 15) * 4;
            float4 v = *(const float4*)(src + (size_t)(tr * 64 + r) * 1024 + tc * 64 + c0);
            tl[(c0 + 0) * 68 + r] = f32_to_bf16_rne(v.x);
            tl[(c0 + 1) * 68 + r] = f32_to_bf16_rne(v.y);
            tl[(c0 + 2) * 68 + r] = f32_to_bf16_rne(v.z);
            tl[(c0 + 3) * 68 + r] = f32_to_bf16_rne(v.w);
        }
        __syncthreads();
        #pragma unroll
        for (int it = 0; it < 4; ++it) {
            int c  = it * 16 + (tid >> 4);
            int r0 = (tid & 15) * 4;
            ushort4 o;
            o.x = tl[c * 68 + r0 + 0]; o.y = tl[c * 68 + r0 + 1];
            o.z = tl[c * 68 + r0 + 2]; o.w = tl[c * 68 + r0 + 3];
            *(ushort4*)(w16 + slot * 1048576 + (size_t)(tc * 64 + c) * 1024 + tr * 64 + r0) = o;
        }
    } else if (b < 10000) {
        // bfinal[row] = bo[row] + dot(Wo[row,:], bv)
        int bb = b - 9984;
        int lane = tid & 63, wv_ = tid >> 6;
        int rowBase = bb * 64 + wv_ * 16;
        for (int rr = 0; rr < 16; ++rr) {
            int row = rowBase + rr;
            float partial = 0.f;
            #pragma unroll
            for (int t2 = 0; t2 < 16; ++t2) {
                int h = t2 * 64 + lane;
                partial += Wo[(size_t)row * 1024 + h] * bv[h];
            }
            #pragma unroll
            for (int off = 32; off > 0; off >>= 1)
                partial += __shfl_xor(partial, off, 64);
            if (lane == 0) bfinal[row] = bo[row] + partial;
        }
    } else {
        int i = (b - 10000) * 1024 + tid * 4;
        *(float4*)(rsum + i) = float4{0.f, 0.f, 0.f, 0.f};
    }
}

// ---------------------------------------------------------------------------
// Proven 128^2 K-loop (R5 codegen) — gf, qgv, scores.
// ---------------------------------------------------------------------------
__device__ __forceinline__ void gemm_core(
    const unsigned short* __restrict__ Ab,
    const unsigned short* __restrict__ Bb,
    unsigned short* ldsA, unsigned short* ldsB,
    int mBase, int nBase, int lane, int wave, int K, f32x4 (&acc)[4][4])
{
    const int quad = lane >> 4;
    const int l16  = lane & 15;
    const int wr   = wave >> 1;
    const int wc   = wave & 1;

    for (int k0 = 0; k0 < K; k0 += BK) {
        #pragma unroll
        for (int i = 0; i < 4; ++i) {
            int base = (i * 4 + wave) * 64;
            int s    = base + lane;
            int row  = s >> 3;
            int col  = ((s ^ (s >> 3)) & 7) * 8;
            __builtin_amdgcn_global_load_lds(
                (const __attribute__((address_space(1))) void*)(Ab + (size_t)(mBase + row) * K + (size_t)(k0 + col)),
                (__attribute__((address_space(3))) void*)(&ldsA[base * 8]),
                16, 0, 0);
        }
        #pragma unroll
        for (int i = 0; i < 4; ++i) {
            int base = (i * 4 + wave) * 64;
            int s    = base + lane;
            int row  = s >> 3;
            int col  = ((s ^ (s >> 3)) & 7) * 8;
            __builtin_amdgcn_global_load_lds(
                (const __attribute__((address_space(1))) void*)(Bb + (size_t)(nBase + row) * K + (size_t)(k0 + col)),
                (__attribute__((address_space(3))) void*)(&ldsB[base * 8]),
                16, 0, 0);
        }
        __syncthreads();

        #pragma unroll
        for (int kk = 0; kk < 2; ++kk) {
            bf16x8 af[4], bfv[4];
            #pragma unroll
            for (int mi = 0; mi < 4; ++mi) {
                int r = wr * 64 + mi * 16 + l16;
                int c = kk * 4 + quad;
                af[mi] = *(const bf16x8*)(&ldsA[r * BK + (((c ^ r) & 7) << 3)]);
            }
            #pragma unroll
            for (int ni = 0; ni < 4; ++ni) {
                int r = wc * 64 + ni * 16 + l16;
                int c = kk * 4 + quad;
                bfv[ni] = *(const bf16x8*)(&ldsB[r * BK + (((c ^ r) & 7) << 3)]);
            }
            #pragma unroll
            for (int mi = 0; mi < 4; ++mi)
                #pragma unroll
                for (int ni = 0; ni < 4; ++ni)
                    acc[mi][ni] = __builtin_amdgcn_mfma_f32_16x16x32_bf16(
                        af[mi], bfv[ni], acc[mi][ni], 0, 0, 0);
        }
        __syncthreads();
    }
}

// ---------------------------------------------------------------------------
// Small dispatch (144 blocks):
//   [0,64)    Gt = WkT.(WqT)^T
//   [64,128)  F  = Wo.(WvT)^T
//   [128,144) g0[j] = sum_h bq[h]*Wk[h,j] = dot(bq, WkT row j)  — coalesced
//             bf16x8 row reads from the already-transposed WkT; bq slices
//             hoisted per lane. (bq = 0 in harness inputs -> g0 = 0 exact.)
// ---------------------------------------------------------------------------
__global__ __launch_bounds__(256) void gemm_gf(
    const unsigned short* __restrict__ w16,
    unsigned short* __restrict__ Gt16, unsigned short* __restrict__ F16,
    const float* __restrict__ bq, float* __restrict__ g0)
{
    const int l = blockIdx.x, tid = threadIdx.x;
    if (l < 128) {
        __shared__ unsigned short ldsA[BM * BK];
        __shared__ unsigned short ldsB[BN * BK];
        const unsigned short *Ab, *Bb;
        unsigned short* Cb;
        int f;
        if (l < 64) { f = l;      Ab = w16 + (size_t)1 * 1048576; Bb = w16;                        Cb = Gt16; }
        else        { f = l - 64; Ab = w16 + (size_t)2 * 1048576; Bb = w16 + (size_t)3 * 1048576; Cb = F16;  }
        int mBase = (f >> 3) * BM, nBase = (f & 7) * BN;

        const int lane = tid & 63, wave = tid >> 6;
        const int quad = lane >> 4, l16 = lane & 15;
        const int wr = wave >> 1, wc = wave & 1;

        f32x4 acc[4][4] = {};
        gemm_core(Ab, Bb, ldsA, ldsB, mBase, nBase, lane, wave, 1024, acc);

        #pragma unroll
        for (int mi = 0; mi < 4; ++mi)
            #pragma unroll
            for (int ni = 0; ni < 4; ++ni) {
                int col = nBase + wc * 64 + ni * 16 + l16;
                #pragma unroll
                for (int r = 0; r < 4; ++r) {
                    int row = mBase + wr * 64 + mi * 16 + quad * 4 + r;
                    Cb[(size_t)row * 1024 + col] = f32_to_bf16_rne(acc[mi][ni][r]);
                }
            }
    } else {
        // g0 rows: 16 blocks x 4 waves x 16 rows = 1024
        int rb = l - 128;
        int lane = tid & 63, w = tid >> 6;
        const unsigned short* WkT = w16 + (size_t)1 * 1048576;
        float bq0[8], bq1[8];
        #pragma unroll
        for (int i = 0; i < 8; ++i) {
            bq0[i] = bq[lane * 8 + i];
            bq1[i] = bq[512 + lane * 8 + i];
        }
        for (int rr = 0; rr < 16; ++rr) {
            int j = (rb * 4 + w) * 16 + rr;
            bf16x8 a0 = *(const bf16x8*)(WkT + (size_t)j * 1024 + lane * 8);
            bf16x8 a1 = *(const bf16x8*)(WkT + (size_t)j * 1024 + 512 + lane * 8);
            float partial = 0.f;
            #pragma unroll
            for (int i = 0; i < 8; ++i)
                partial += bq0[i] * (float)a0[i] + bq1[i] * (float)a1[i];
            #pragma unroll
            for (int off = 32; off > 0; off >>= 1)
                partial += __shfl_xor(partial, off, 64);
            if (lane == 0) g0[j] = partial;
        }
    }
}

// ---------------------------------------------------------------------------
// qg = x.Gt^T + g0 (512 tiles) and Vot[b] = F.x_b^T (512 tiles), merged.
// 1024 blocks, XCD-contiguous.
// ---------------------------------------------------------------------------
__global__ __launch_bounds__(256) void gemm_qgv(
    const unsigned short* __restrict__ x16,
    const unsigned short* __restrict__ Gt16,
    const unsigned short* __restrict__ F16,
    const float* __restrict__ g0,
    unsigned short* __restrict__ qg16,
    unsigned short* __restrict__ vot16)
{
    __shared__ unsigned short ldsA[BM * BK];
    __shared__ unsigned short ldsB[BN * BK];

    int l   = blockIdx.x;                 // 1024 = 8 * 128
    int idx = (l & 7) * 128 + (l >> 3);   // XCD-contiguous

    const unsigned short *Ab, *Bb;
    unsigned short* Cb;
    const float* bias;
    int mBase, nBase, Cstride;
    if (idx < 512) {
        // qg: M=8192 (both batches), N=1024, K=1024
        mBase = (idx >> 3) * BM; nBase = (idx & 7) * BN;
        Ab = x16; Bb = Gt16; Cb = qg16; bias = g0; Cstride = 1024;
    } else {
        // Vot[b]: M=1024, N=4096, K=1024
        int v = idx - 512;
        int zb = v >> 8, t2 = v & 255;
        mBase = (t2 >> 5) * BM; nBase = (t2 & 31) * BN;
        Ab = F16; Bb = x16 + (size_t)zb * 4096 * 1024;
        Cb = vot16 + (size_t)zb * 1024 * 4096; bias = nullptr; Cstride = 4096;
    }

    const int tid  = threadIdx.x;
    const int lane = tid & 63;
    const int wave = tid >> 6;
    const int quad = lane >> 4;
    const int l16  = lane & 15;
    const int wr   = wave >> 1;
    const int wc   = wave & 1;

    f32x4 acc[4][4] = {};
    gemm_core(Ab, Bb, ldsA, ldsB, mBase, nBase, lane, wave, 1024, acc);

    #pragma unroll
    for (int mi = 0; mi < 4; ++mi)
        #pragma unroll
        for (int ni = 0; ni < 4; ++ni) {
            int col = nBase + wc * 64 + ni * 16 + l16;
            float b = bias ? bias[col] : 0.f;
            #pragma unroll
            for (int r = 0; r < 4; ++r) {
                int row = mBase + wr * 64 + mi * 16 + quad * 4 + r;
                Cb[(size_t)row * Cstride + col] = f32_to_bf16_rne(acc[mi][ni][r] + b);
            }
        }
}

// ---------------------------------------------------------------------------
// scores: z-batched A.Bt^T, 128^2 proven path (fastest measured: ~90-93 µs).
// C bf16 = exp(acc * alpha), atomic fp32 rowsums.
// ---------------------------------------------------------------------------
__global__ __launch_bounds__(256) void gemm_sc(
    const unsigned short* __restrict__ A,
    const unsigned short* __restrict__ Bt,
    unsigned short* __restrict__ C,
    float* __restrict__ rowsum,
    float alpha, int M, int N, int K,
    long long aZ, long long bZ, long long cZ)
{
    __shared__ unsigned short ldsA[BM * BK];
    __shared__ unsigned short ldsB[BN * BK];

    const int NB = gridDim.x, MBt = gridDim.y;
    int l  = blockIdx.x + gridDim.x * (blockIdx.y + gridDim.y * blockIdx.z);
    int xcd = l & 7;
    int t   = l >> 3;
    int MBX = MBt >> 1;
    int NBX = NB >> 2;
    int mbl = t % MBX;
    int r1  = t / MBX;
    int nbi = r1 % NBX;
    int zb  = r1 / NBX;
    int mb  = (xcd >> 2) * MBX + mbl;
    int nb  = (xcd & 3) * NBX + nbi;

    const unsigned short* Ab = A  + (size_t)zb * aZ;
    const unsigned short* Bb = Bt + (size_t)zb * bZ;

    const int tid  = threadIdx.x;
    const int lane = tid & 63;
    const int wave = tid >> 6;
    const int quad = lane >> 4;
    const int l16  = lane & 15;
    const int wr   = wave >> 1;
    const int wc   = wave & 1;
    const int mBase = mb * BM;
    const int nBase = nb * BN;

    f32x4 acc[4][4] = {};
    gemm_core(Ab, Bb, ldsA, ldsB, mBase, nBase, lane, wave, K, acc);

    unsigned short* Pz = C + (size_t)zb * cZ;
    float* rs = rowsum + (size_t)zb * M;
    #pragma unroll
    for (int mi = 0; mi < 4; ++mi) {
        #pragma unroll
        for (int r = 0; r < 4; ++r) {
            int row = mBase + wr * 64 + mi * 16 + quad * 4 + r;
            float e[4];
            float partial = 0.f;
            #pragma unroll
            for (int ni = 0; ni < 4; ++ni) {
                e[ni] = __expf(acc[mi][ni][r] * alpha);
                partial += e[ni];
            }
            #pragma unroll
            for (int ni = 0; ni < 4; ++ni) {
                int col = nBase + wc * 64 + ni * 16 + l16;
                Pz[(size_t)row * N + col] = f32_to_bf16_rne(e[ni]);
            }
            #pragma unroll
            for (int off = 1; off < 16; off <<= 1)
                partial += __shfl_xor(partial, off, 64);
            if (l16 == 0) atomicAdd(&rs[row], partial);
        }
    }
}

// ---------------------------------------------------------------------------
// final: phase-split GEMM (R10-corrected m201 schedule), 128x256, K=4096.
// 8 waves (2m x 4n), BK=64, double-buffered xor-swizzled LDS,
// global_load_lds(16B), counted vmcnt once per K-tile (never 0 in steady
// state). Phase = {ds_read subtile + stage issue + [vmcnt] -> s_barrier ->
// lgkmcnt(0)+sched_barrier(0) -> setprio(1) 16xMFMA setprio(0) -> s_barrier}.
// C fp32 = acc/rowsum + b0.
// ---------------------------------------------------------------------------
template <int BMt, int BNt>
__global__ __launch_bounds__(512) void gemm8p(
    const unsigned short* __restrict__ A,
    const unsigned short* __restrict__ Bt,
    float* __restrict__ C,
    const float* __restrict__ b0, const float* __restrict__ rowsum,
    int M, int N, int K,
    long long aZ, long long bZ, long long cZ,
    int MBt, int NB)
{
    constexpr int RW  = BMt / 2;           // rows per wave
    constexpr int CW  = BNt / 4;           // cols per wave (= 64)
    constexpr int MI  = RW / 16;           // m-frags per wave
    constexpr int NI  = CW / 16;           // n-frags per wave (= 4)
    constexpr int NPH = MI / 2;            // phases per K-tile
    constexpr int BL  = (BNt * 64 / 512) / 8;  // B loads/wave/K-tile (= 4)
    constexpr int NWT = BL + NPH - 1;      // steady-state counted vmcnt

    __shared__ __align__(16) unsigned short ldsA[2][BMt * 64];
    __shared__ __align__(16) unsigned short ldsB[2][BNt * 64];

    const int l   = blockIdx.x;
    const int xcd = l & 7;
    const int t   = l >> 3;
    const int MBX = MBt >> 1;
    const int NBX = NB >> 2;
    const int mbl = t % MBX;
    const int r1  = t / MBX;
    const int nbi = r1 % NBX;
    const int zb  = r1 / NBX;
    const int mb  = (xcd >> 2) * MBX + mbl;
    const int nb  = (xcd & 3) * NBX + nbi;

    const unsigned short* Ab = A  + (size_t)zb * aZ;
    const unsigned short* Bb = Bt + (size_t)zb * bZ;

    const int tid  = threadIdx.x;
    const int lane = tid & 63;
    const int wave = tid >> 6;
    const int quad = lane >> 4;
    const int l16  = lane & 15;
    const int wr   = wave >> 2;            // 0..1
    const int wc   = wave & 3;             // 0..3
    const int mBase = mb * BMt;
    const int nBase = nb * BNt;
    const int NT    = K >> 6;

    // each wave stages one 8-row octet per A-strip-half and BL octets of B
    const int aRow0 = ((wave & 4) ? RW : 0) + (wave & 3) * 8;

    auto stageA = [&](int p, int kt, int q) {
        const int rowbase = aRow0 + q * 32;
        const int row = rowbase + (lane >> 3);
        const int col = (((lane & 7) ^ row) & 7) << 3;   // pre-swizzled source
        __builtin_amdgcn_global_load_lds(
            (const __attribute__((address_space(1))) void*)(
                Ab + (size_t)(mBase + row) * K + (size_t)((kt << 6) + col)),
            (__attribute__((address_space(3))) void*)(&ldsA[p][rowbase * 64]),
            16, 0, 0);
    };
    auto stageB = [&](int p, int kt) {
        #pragma unroll
        for (int i = 0; i < BL; ++i) {
            const int g   = wave * BL + i;
            const int row = (g << 3) + (lane >> 3);
            const int col = (((lane & 7) ^ row) & 7) << 3;
            __builtin_amdgcn_global_load_lds(
                (const __attribute__((address_space(1))) void*)(
                    Bb + (size_t)(nBase + row) * K + (size_t)((kt << 6) + col)),
                (__attribute__((address_space(3))) void*)(&ldsB[p][g << 9]),
                16, 0, 0);
        }
    };

    bf16x8 bf[NI][2];
    bf16x8 af[2][2];
    auto ldB = [&](int p) {
        #pragma unroll
        for (int n2 = 0; n2 < NI; ++n2)
            #pragma unroll
            for (int kk = 0; kk < 2; ++kk) {
                const int r = wc * CW + n2 * 16 + l16;
                const int c = kk * 4 + quad;
                bf[n2][kk] = *(const bf16x8*)&ldsB[p][r * 64 + (((c ^ r) & 7) << 3)];
            }
    };
    auto ldA = [&](int p, int q) {
        #pragma unroll
        for (int m2 = 0; m2 < 2; ++m2)
            #pragma unroll
            for (int kk = 0; kk < 2; ++kk) {
                const int r = wr * RW + (q * 2 + m2) * 16 + l16;
                const int c = kk * 4 + quad;
                af[m2][kk] = *(const bf16x8*)&ldsA[p][r * 64 + (((c ^ r) & 7) << 3)];
            }
    };

    f32x4 acc[MI][NI] = {};

    // ---- prologue: tile0 fully + tile1 all but its last strip ----
    stageB(0, 0);
    #pragma unroll
    for (int q = 0; q < NPH; ++q) stageA(0, 0, q);
    if (NT > 1) {
        stageB(1, 1);
        #pragma unroll
        for (int q = 0; q < NPH - 1; ++q) stageA(1, 1, q);
        asm volatile("s_waitcnt vmcnt(%0)" :: "n"(NWT) : "memory");
    } else {
        asm volatile("s_waitcnt vmcnt(0)" ::: "memory");
    }
    __builtin_amdgcn_s_barrier();

    // ---- main loop ----
    for (int kt = 0; kt < NT; ++kt) {
        const int p = kt & 1;
        #pragma unroll
        for (int q = 0; q < NPH; ++q) {
            if (q == 0) ldB(p);
            ldA(p, q);
            if (q == 0) {
                if (kt + 1 < NT) stageA(p ^ 1, kt + 1, NPH - 1);
            } else if (q == 1) {
                if (kt + 2 < NT) { stageB(p, kt + 2); stageA(p, kt + 2, 0); }
            } else {
                if (kt + 2 < NT) stageA(p, kt + 2, q - 1);
            }
            if (q == NPH - 1) {
                if (kt + 2 < NT) {
                    asm volatile("s_waitcnt vmcnt(%0)" :: "n"(NWT) : "memory");
                } else if (kt + 1 < NT) {
                    asm volatile("s_waitcnt vmcnt(0)" ::: "memory");
                }
            }
            __builtin_amdgcn_s_barrier();
            // pin all of this wave's ds_reads complete before the end
            // barrier (slot-reuse race-freedom) and keep MFMAs from
            // hoisting above it (rule #18).
            asm volatile("s_waitcnt lgkmcnt(0)" ::: "memory");
            __builtin_amdgcn_sched_barrier(0);
            __builtin_amdgcn_s_setprio(1);
            #pragma unroll
            for (int m2 = 0; m2 < 2; ++m2)
                #pragma unroll
                for (int n2 = 0; n2 < NI; ++n2)
                    #pragma unroll
                    for (int kk = 0; kk < 2; ++kk)
                        acc[q * 2 + m2][n2] = __builtin_amdgcn_mfma_f32_16x16x32_bf16(
                            af[m2][kk], bf[n2][kk], acc[q * 2 + m2][n2], 0, 0, 0);
            __builtin_amdgcn_s_setprio(0);
            __builtin_amdgcn_s_barrier();
        }
    }

    // ---- epilogue. C/D layout: col = l16, row = quad*4 + reg ----
    {
        float* Cz = C + (size_t)zb * cZ;
        const float* rs = rowsum + (size_t)zb * M;
        #pragma unroll
        for (int mi = 0; mi < MI; ++mi) {
            #pragma unroll
            for (int r = 0; r < 4; ++r) {
                const int row = mBase + wr * RW + mi * 16 + quad * 4 + r;
                const float inv = 1.f / rs[row];
                #pragma unroll
                for (int ni = 0; ni < NI; ++ni) {
                    const int col = nBase + wc * CW + ni * 16 + l16;
                    Cz[(size_t)row * N + col] = acc[mi][ni][r] * inv + b0[col];
                }
            }
        }
    }
}

// ---------------------------------------------------------------------------
extern "C" void kernel_launch(void* const* d_in, const int* in_sizes, int n_in,
                              void* d_out, int out_size, void* d_ws, size_t ws_size,
                              hipStream_t stream)
{
    const float* x  = (const float*)d_in[0];
    const float* Wq = (const float*)d_in[1];
    const float* bq = (const float*)d_in[2];
    const float* Wk = (const float*)d_in[3];
    const float* Wv = (const float*)d_in[5];
    const float* bv = (const float*)d_in[6];
    const float* Wo = (const float*)d_in[7];
    const float* bo = (const float*)d_in[8];
    float* out = (float*)d_out;

    const int S = 4096, H = 1024, Bsz = 2;
    const int M = Bsz * S;   // 8192

    char* p = (char*)d_ws;
    auto alloc = [&](size_t bytes) -> char* {
        char* r = p; p += (bytes + 255) & ~(size_t)255; return r;
    };
    // footprint ~124 MiB (ws >= 153 MiB proven in R2)
    unsigned short* w16   = (unsigned short*)alloc((size_t)4 * H * H * 2);  // WqT|WkT|Wo|WvT
    unsigned short* F16   = (unsigned short*)alloc((size_t)H * H * 2);
    unsigned short* Gt16  = (unsigned short*)alloc((size_t)H * H * 2);
    unsigned short* qg16  = (unsigned short*)alloc((size_t)M * H * 2);
    unsigned short* vot16 = (unsigned short*)alloc((size_t)Bsz * H * S * 2); // [B][H][S]
    unsigned short* x16   = (unsigned short*)alloc((size_t)M * H * 2);
    float*          rsum  = (float*)alloc((size_t)M * 4);
    float*          bfin  = (float*)alloc((size_t)H * 4);
    float*          g0    = (float*)alloc((size_t)H * 4);
    unsigned short* p16   = (unsigned short*)alloc((size_t)Bsz * S * S * 2);

    // 1) converts + transposes + bfinal + rsum zeroing   (one dispatch)
    cvt_all<<<10008, 256, 0, stream>>>(x, Wq, Wk, Wo, Wv, bv, bo,
                                       x16, w16, rsum, bfin);

    // 2) Gt = WkT.WqT^T, F = Wo.WvT^T, g0 = bq^T Wk  (one dispatch)
    gemm_gf<<<144, 256, 0, stream>>>(w16, Gt16, F16, bq, g0);

    // 3) qg = x.Gt^T + g0  and  Vot[b] = F.x_b^T
    gemm_qgv<<<1024, 256, 0, stream>>>(x16, Gt16, F16, g0, qg16, vot16);

    // 4) P_un[b] = exp((qg.x_b^T)/8) + atomic rowsums  (128^2 proven path)
    gemm_sc<<<dim3(S / BN, S / BM, 2), 256, 0, stream>>>(
        qg16, x16, p16, rsum, 0.125f, S, S, 1024,
        (long long)S * H, (long long)S * H, (long long)S * S);

    // 5) out[b] = (P_un . Vot^T)/rowsum + bfinal   (128x256 phase-split)
    gemm8p<128, 256><<<256, 512, 0, stream>>>(
        p16, vot16, out, bfin, rsum, S, H, 4096,
        (long long)S * S, (long long)H * S, (long long)S * H, 32, 4);
}

// Round 8
// 343.381 us; speedup vs baseline: 1.0027x; 1.0027x over previous
//
#include <hip/hip_runtime.h>
#include <stdint.h>

// ---------------------------------------------------------------------------
// DistributedAttention on MI355X (gfx950)
//   q = x Wq^T + bq ; k = x Wk^T + bk ; v = x Wv^T + bv
//   P = softmax(q k^T / 8) ; out = P v Wo^T + bo
// Factorizations:
//   F  = Wo . Wv                  (2.1 GF, replaces the 17.2 GF v-proj)  [R7]
//   Vot= F . x^T per batch        ([H][S] bf16)                          [R7]
//   G  = Wq^T . Wk  (batch-indep) ; qg = x . G + g0, g0 = bq^T Wk        [R11]
//   scores = qg . x^T   (row-constant terms cancel in softmax)           [R12]
//   P_un = exp(scores / 8)        (bf16 + atomic fp32 rowsums)
//   out  = (P_un . Vot^T)/rowsum + bfinal,  bfinal = bo + Wo.bv
// R16: ROOT CAUSE of the failed 8-phase ports found in the counters:
//   gemm8p<3,256,256> needs 128 VGPRs of acc alone but R9/R13 report
//   VGPR_Count=116 -> the accumulators were SPILLED TO SCRATCH (rule #20
//   failure mode, ~5x slowdown measured in learn_hip m214-r286). Cause:
//   __launch_bounds__(512) without the waves/EU arg caps the allocator at
//   default occupancy, though LDS=128KiB already limits to 1 blk/CU
//   (2 waves/SIMD -> 256 VGPRs available).
//   Fix: __launch_bounds__(512, 2) on gemm8p; scores back on
//   gemm8p<3,256,256> (numerics harness-proven in R9/R13, absmax
//   0.0703125), final stays gemm8p<6,128,256>.
//   Verification signal next round: scores VGPR_Count ~190-240, else revert.
// ---------------------------------------------------------------------------

typedef __bf16 bf16x8 __attribute__((ext_vector_type(8)));
typedef float  f32x4  __attribute__((ext_vector_type(4)));

__device__ __forceinline__ unsigned short f32_to_bf16_rne(float f) {
    uint32_t u = __builtin_bit_cast(uint32_t, f);
    uint32_t r = (u + 0x7FFFu + ((u >> 16) & 1u)) >> 16;
    return (unsigned short)r;
}

#define BM 128
#define BN 128
#define BK 64

// ---------------------------------------------------------------------------
// One-dispatch prep, 10008 blocks:
//   [0,8192)        x fp32 -> x16 bf16
//   [8192,9216)     Wo straight convert -> w16 slot 2
//   [9216,9984)     WqT, WkT, WvT 64x64-tile transposes -> slots 0,1,3
//   [9984,10000)    bfinal = bo + Wo.bv
//   [10000,10008)   zero rsum
// ---------------------------------------------------------------------------
__global__ __launch_bounds__(256) void cvt_all(
    const float* __restrict__ x,
    const float* __restrict__ Wq, const float* __restrict__ Wk,
    const float* __restrict__ Wo, const float* __restrict__ Wv,
    const float* __restrict__ bv, const float* __restrict__ bo,
    unsigned short* __restrict__ x16, unsigned short* __restrict__ w16,
    float* __restrict__ rsum, float* __restrict__ bfinal)
{
    const int b = blockIdx.x, tid = threadIdx.x;
    if (b < 8192) {
        int i = (b * 256 + tid) * 4;
        float4 v = *(const float4*)(x + i);
        ushort4 o;
        o.x = f32_to_bf16_rne(v.x); o.y = f32_to_bf16_rne(v.y);
        o.z = f32_to_bf16_rne(v.z); o.w = f32_to_bf16_rne(v.w);
        *(ushort4*)(x16 + i) = o;
    } else if (b < 9216) {
        int i = ((b - 8192) * 256 + tid) * 4;
        float4 v = *(const float4*)(Wo + i);
        ushort4 o;
        o.x = f32_to_bf16_rne(v.x); o.y = f32_to_bf16_rne(v.y);
        o.z = f32_to_bf16_rne(v.z); o.w = f32_to_bf16_rne(v.w);
        *(ushort4*)(w16 + (size_t)2 * 1048576 + i) = o;
    } else if (b < 9984) {
        // transpose one 64x64 tile of {Wq,Wk,Wv} into w16 slot {0,1,3}
        __shared__ unsigned short tl[64 * 68];   // [c][r], stride 68
        int t = b - 9216;
        int which = t >> 8;                      // 0:Wq 1:Wk 2:Wv
        const float* src = which == 0 ? Wq : which == 1 ? Wk : Wv;
        size_t slot = which == 0 ? 0 : which == 1 ? 1 : 3;
        int tile = t & 255, tr = tile >> 4, tc = tile & 15;
        #pragma unroll
        for (int it = 0; it < 4; ++it) {
            int r  = it * 16 + (tid >> 4);
            int c0 = (tid & 15) * 4;
            float4 v = *(const float4*)(src + (size_t)(tr * 64 + r) * 1024 + tc * 64 + c0);
            tl[(c0 + 0) * 68 + r] = f32_to_bf16_rne(v.x);
            tl[(c0 + 1) * 68 + r] = f32_to_bf16_rne(v.y);
            tl[(c0 + 2) * 68 + r] = f32_to_bf16_rne(v.z);
            tl[(c0 + 3) * 68 + r] = f32_to_bf16_rne(v.w);
        }
        __syncthreads();
        #pragma unroll
        for (int it = 0; it < 4; ++it) {
            int c  = it * 16 + (tid >> 4);
            int r0 = (tid & 15) * 4;
            ushort4 o;
            o.x = tl[c * 68 + r0 + 0]; o.y = tl[c * 68 + r0 + 1];
            o.z = tl[c * 68 + r0 + 2]; o.w = tl[c * 68 + r0 + 3];
            *(ushort4*)(w16 + slot * 1048576 + (size_t)(tc * 64 + c) * 1024 + tr * 64 + r0) = o;
        }
    } else if (b < 10000) {
        // bfinal[row] = bo[row] + dot(Wo[row,:], bv)
        int bb = b - 9984;
        int lane = tid & 63, wv_ = tid >> 6;
        int rowBase = bb * 64 + wv_ * 16;
        for (int rr = 0; rr < 16; ++rr) {
            int row = rowBase + rr;
            float partial = 0.f;
            #pragma unroll
            for (int t2 = 0; t2 < 16; ++t2) {
                int h = t2 * 64 + lane;
                partial += Wo[(size_t)row * 1024 + h] * bv[h];
            }
            #pragma unroll
            for (int off = 32; off > 0; off >>= 1)
                partial += __shfl_xor(partial, off, 64);
            if (lane == 0) bfinal[row] = bo[row] + partial;
        }
    } else {
        int i = (b - 10000) * 1024 + tid * 4;
        *(float4*)(rsum + i) = float4{0.f, 0.f, 0.f, 0.f};
    }
}

// ---------------------------------------------------------------------------
// Proven 128^2 K-loop (R5 codegen) — gf, qgv.
// ---------------------------------------------------------------------------
__device__ __forceinline__ void gemm_core(
    const unsigned short* __restrict__ Ab,
    const unsigned short* __restrict__ Bb,
    unsigned short* ldsA, unsigned short* ldsB,
    int mBase, int nBase, int lane, int wave, int K, f32x4 (&acc)[4][4])
{
    const int quad = lane >> 4;
    const int l16  = lane & 15;
    const int wr   = wave >> 1;
    const int wc   = wave & 1;

    for (int k0 = 0; k0 < K; k0 += BK) {
        #pragma unroll
        for (int i = 0; i < 4; ++i) {
            int base = (i * 4 + wave) * 64;
            int s    = base + lane;
            int row  = s >> 3;
            int col  = ((s ^ (s >> 3)) & 7) * 8;
            __builtin_amdgcn_global_load_lds(
                (const __attribute__((address_space(1))) void*)(Ab + (size_t)(mBase + row) * K + (size_t)(k0 + col)),
                (__attribute__((address_space(3))) void*)(&ldsA[base * 8]),
                16, 0, 0);
        }
        #pragma unroll
        for (int i = 0; i < 4; ++i) {
            int base = (i * 4 + wave) * 64;
            int s    = base + lane;
            int row  = s >> 3;
            int col  = ((s ^ (s >> 3)) & 7) * 8;
            __builtin_amdgcn_global_load_lds(
                (const __attribute__((address_space(1))) void*)(Bb + (size_t)(nBase + row) * K + (size_t)(k0 + col)),
                (__attribute__((address_space(3))) void*)(&ldsB[base * 8]),
                16, 0, 0);
        }
        __syncthreads();

        #pragma unroll
        for (int kk = 0; kk < 2; ++kk) {
            bf16x8 af[4], bfv[4];
            #pragma unroll
            for (int mi = 0; mi < 4; ++mi) {
                int r = wr * 64 + mi * 16 + l16;
                int c = kk * 4 + quad;
                af[mi] = *(const bf16x8*)(&ldsA[r * BK + (((c ^ r) & 7) << 3)]);
            }
            #pragma unroll
            for (int ni = 0; ni < 4; ++ni) {
                int r = wc * 64 + ni * 16 + l16;
                int c = kk * 4 + quad;
                bfv[ni] = *(const bf16x8*)(&ldsB[r * BK + (((c ^ r) & 7) << 3)]);
            }
            #pragma unroll
            for (int mi = 0; mi < 4; ++mi)
                #pragma unroll
                for (int ni = 0; ni < 4; ++ni)
                    acc[mi][ni] = __builtin_amdgcn_mfma_f32_16x16x32_bf16(
                        af[mi], bfv[ni], acc[mi][ni], 0, 0, 0);
        }
        __syncthreads();
    }
}

// ---------------------------------------------------------------------------
// Small dispatch (144 blocks):
//   [0,64)    Gt = WkT.(WqT)^T
//   [64,128)  F  = Wo.(WvT)^T
//   [128,144) g0[j] = dot(bq, WkT row j)  (coalesced bf16x8 row reads)
// ---------------------------------------------------------------------------
__global__ __launch_bounds__(256) void gemm_gf(
    const unsigned short* __restrict__ w16,
    unsigned short* __restrict__ Gt16, unsigned short* __restrict__ F16,
    const float* __restrict__ bq, float* __restrict__ g0)
{
    const int l = blockIdx.x, tid = threadIdx.x;
    if (l < 128) {
        __shared__ unsigned short ldsA[BM * BK];
        __shared__ unsigned short ldsB[BN * BK];
        const unsigned short *Ab, *Bb;
        unsigned short* Cb;
        int f;
        if (l < 64) { f = l;      Ab = w16 + (size_t)1 * 1048576; Bb = w16;                        Cb = Gt16; }
        else        { f = l - 64; Ab = w16 + (size_t)2 * 1048576; Bb = w16 + (size_t)3 * 1048576; Cb = F16;  }
        int mBase = (f >> 3) * BM, nBase = (f & 7) * BN;

        const int lane = tid & 63, wave = tid >> 6;
        const int quad = lane >> 4, l16 = lane & 15;
        const int wr = wave >> 1, wc = wave & 1;

        f32x4 acc[4][4] = {};
        gemm_core(Ab, Bb, ldsA, ldsB, mBase, nBase, lane, wave, 1024, acc);

        #pragma unroll
        for (int mi = 0; mi < 4; ++mi)
            #pragma unroll
            for (int ni = 0; ni < 4; ++ni) {
                int col = nBase + wc * 64 + ni * 16 + l16;
                #pragma unroll
                for (int r = 0; r < 4; ++r) {
                    int row = mBase + wr * 64 + mi * 16 + quad * 4 + r;
                    Cb[(size_t)row * 1024 + col] = f32_to_bf16_rne(acc[mi][ni][r]);
                }
            }
    } else {
        // g0 rows: 16 blocks x 4 waves x 16 rows = 1024
        int rb = l - 128;
        int lane = tid & 63, w = tid >> 6;
        const unsigned short* WkT = w16 + (size_t)1 * 1048576;
        float bq0[8], bq1[8];
        #pragma unroll
        for (int i = 0; i < 8; ++i) {
            bq0[i] = bq[lane * 8 + i];
            bq1[i] = bq[512 + lane * 8 + i];
        }
        for (int rr = 0; rr < 16; ++rr) {
            int j = (rb * 4 + w) * 16 + rr;
            bf16x8 a0 = *(const bf16x8*)(WkT + (size_t)j * 1024 + lane * 8);
            bf16x8 a1 = *(const bf16x8*)(WkT + (size_t)j * 1024 + 512 + lane * 8);
            float partial = 0.f;
            #pragma unroll
            for (int i = 0; i < 8; ++i)
                partial += bq0[i] * (float)a0[i] + bq1[i] * (float)a1[i];
            #pragma unroll
            for (int off = 32; off > 0; off >>= 1)
                partial += __shfl_xor(partial, off, 64);
            if (lane == 0) g0[j] = partial;
        }
    }
}

// ---------------------------------------------------------------------------
// qg = x.Gt^T + g0 (512 tiles) and Vot[b] = F.x_b^T (512 tiles), merged.
// 1024 blocks, XCD-contiguous.
// ---------------------------------------------------------------------------
__global__ __launch_bounds__(256) void gemm_qgv(
    const unsigned short* __restrict__ x16,
    const unsigned short* __restrict__ Gt16,
    const unsigned short* __restrict__ F16,
    const float* __restrict__ g0,
    unsigned short* __restrict__ qg16,
    unsigned short* __restrict__ vot16)
{
    __shared__ unsigned short ldsA[BM * BK];
    __shared__ unsigned short ldsB[BN * BK];

    int l   = blockIdx.x;                 // 1024 = 8 * 128
    int idx = (l & 7) * 128 + (l >> 3);   // XCD-contiguous

    const unsigned short *Ab, *Bb;
    unsigned short* Cb;
    const float* bias;
    int mBase, nBase, Cstride;
    if (idx < 512) {
        // qg: M=8192 (both batches), N=1024, K=1024
        mBase = (idx >> 3) * BM; nBase = (idx & 7) * BN;
        Ab = x16; Bb = Gt16; Cb = qg16; bias = g0; Cstride = 1024;
    } else {
        // Vot[b]: M=1024, N=4096, K=1024
        int v = idx - 512;
        int zb = v >> 8, t2 = v & 255;
        mBase = (t2 >> 5) * BM; nBase = (t2 & 31) * BN;
        Ab = F16; Bb = x16 + (size_t)zb * 4096 * 1024;
        Cb = vot16 + (size_t)zb * 1024 * 4096; bias = nullptr; Cstride = 4096;
    }

    const int tid  = threadIdx.x;
    const int lane = tid & 63;
    const int wave = tid >> 6;
    const int quad = lane >> 4;
    const int l16  = lane & 15;
    const int wr   = wave >> 1;
    const int wc   = wave & 1;

    f32x4 acc[4][4] = {};
    gemm_core(Ab, Bb, ldsA, ldsB, mBase, nBase, lane, wave, 1024, acc);

    #pragma unroll
    for (int mi = 0; mi < 4; ++mi)
        #pragma unroll
        for (int ni = 0; ni < 4; ++ni) {
            int col = nBase + wc * 64 + ni * 16 + l16;
            float b = bias ? bias[col] : 0.f;
            #pragma unroll
            for (int r = 0; r < 4; ++r) {
                int row = mBase + wr * 64 + mi * 16 + quad * 4 + r;
                Cb[(size_t)row * Cstride + col] = f32_to_bf16_rne(acc[mi][ni][r] + b);
            }
        }
}

// ---------------------------------------------------------------------------
// Phase-split GEMM (R10-corrected m201 schedule) with the R16 register fix:
// __launch_bounds__(512, 2) — LDS already limits to 1 blk/CU (2 waves/SIMD),
// so allow the allocator 256 VGPRs; without it the 256x256 instance spilled
// its 128-VGPR accumulator to scratch (R9/R13: VGPR_Count=116 < acc size).
// 8 waves (2m x 4n), BK=64, double-buffered xor-swizzled LDS,
// global_load_lds(16B), counted vmcnt once per K-tile. Phase = {ds_read
// subtile + stage issue + [vmcnt] -> s_barrier -> lgkmcnt(0)+
// sched_barrier(0) -> setprio(1) 16xMFMA setprio(0) -> s_barrier}.
// MODE 3 (scores, 256x256): C bf16 = exp(acc*alpha), atomic fp32 rowsums.
// MODE 6 (final, 128x256):  C fp32 = acc/rowsum + b0.
// ---------------------------------------------------------------------------
template <int MODE, int BMt, int BNt>
__global__ __launch_bounds__(512, 2) void gemm8p(
    const unsigned short* __restrict__ A,
    const unsigned short* __restrict__ Bt,
    void* __restrict__ C,
    const float* __restrict__ b0, float* __restrict__ rowsum,
    float alpha, int M, int N, int K,
    long long aZ, long long bZ, long long cZ,
    int MBt, int NB)
{
    constexpr int RW  = BMt / 2;           // rows per wave
    constexpr int CW  = BNt / 4;           // cols per wave (= 64)
    constexpr int MI  = RW / 16;           // m-frags per wave
    constexpr int NI  = CW / 16;           // n-frags per wave (= 4)
    constexpr int NPH = MI / 2;            // phases per K-tile
    constexpr int BL  = (BNt * 64 / 512) / 8;  // B loads/wave/K-tile (= 4)
    constexpr int NWT = BL + NPH - 1;      // steady-state counted vmcnt

    __shared__ __align__(16) unsigned short ldsA[2][BMt * 64];
    __shared__ __align__(16) unsigned short ldsB[2][BNt * 64];

    const int l   = blockIdx.x;
    const int xcd = l & 7;
    const int t   = l >> 3;
    const int MBX = MBt >> 1;
    const int NBX = NB >> 2;
    const int mbl = t % MBX;
    const int r1  = t / MBX;
    const int nbi = r1 % NBX;
    const int zb  = r1 / NBX;
    const int mb  = (xcd >> 2) * MBX + mbl;
    const int nb  = (xcd & 3) * NBX + nbi;

    const unsigned short* Ab = A  + (size_t)zb * aZ;
    const unsigned short* Bb = Bt + (size_t)zb * bZ;

    const int tid  = threadIdx.x;
    const int lane = tid & 63;
    const int wave = tid >> 6;
    const int quad = lane >> 4;
    const int l16  = lane & 15;
    const int wr   = wave >> 2;            // 0..1
    const int wc   = wave & 3;             // 0..3
    const int mBase = mb * BMt;
    const int nBase = nb * BNt;
    const int NT    = K >> 6;

    // each wave stages one 8-row octet per A-strip-half and BL octets of B
    const int aRow0 = ((wave & 4) ? RW : 0) + (wave & 3) * 8;

    auto stageA = [&](int p, int kt, int q) {
        const int rowbase = aRow0 + q * 32;
        const int row = rowbase + (lane >> 3);
        const int col = (((lane & 7) ^ row) & 7) << 3;   // pre-swizzled source
        __builtin_amdgcn_global_load_lds(
            (const __attribute__((address_space(1))) void*)(
                Ab + (size_t)(mBase + row) * K + (size_t)((kt << 6) + col)),
            (__attribute__((address_space(3))) void*)(&ldsA[p][rowbase * 64]),
            16, 0, 0);
    };
    auto stageB = [&](int p, int kt) {
        #pragma unroll
        for (int i = 0; i < BL; ++i) {
            const int g   = wave * BL + i;
            const int row = (g << 3) + (lane >> 3);
            const int col = (((lane & 7) ^ row) & 7) << 3;
            __builtin_amdgcn_global_load_lds(
                (const __attribute__((address_space(1))) void*)(
                    Bb + (size_t)(nBase + row) * K + (size_t)((kt << 6) + col)),
                (__attribute__((address_space(3))) void*)(&ldsB[p][g << 9]),
                16, 0, 0);
        }
    };

    bf16x8 bf[NI][2];
    bf16x8 af[2][2];
    auto ldB = [&](int p) {
        #pragma unroll
        for (int n2 = 0; n2 < NI; ++n2)
            #pragma unroll
            for (int kk = 0; kk < 2; ++kk) {
                const int r = wc * CW + n2 * 16 + l16;
                const int c = kk * 4 + quad;
                bf[n2][kk] = *(const bf16x8*)&ldsB[p][r * 64 + (((c ^ r) & 7) << 3)];
            }
    };
    auto ldA = [&](int p, int q) {
        #pragma unroll
        for (int m2 = 0; m2 < 2; ++m2)
            #pragma unroll
            for (int kk = 0; kk < 2; ++kk) {
                const int r = wr * RW + (q * 2 + m2) * 16 + l16;
                const int c = kk * 4 + quad;
                af[m2][kk] = *(const bf16x8*)&ldsA[p][r * 64 + (((c ^ r) & 7) << 3)];
            }
    };

    f32x4 acc[MI][NI] = {};

    // ---- prologue: tile0 fully + tile1 all but its last strip ----
    stageB(0, 0);
    #pragma unroll
    for (int q = 0; q < NPH; ++q) stageA(0, 0, q);
    if (NT > 1) {
        stageB(1, 1);
        #pragma unroll
        for (int q = 0; q < NPH - 1; ++q) stageA(1, 1, q);
        asm volatile("s_waitcnt vmcnt(%0)" :: "n"(NWT) : "memory");
    } else {
        asm volatile("s_waitcnt vmcnt(0)" ::: "memory");
    }
    __builtin_amdgcn_s_barrier();

    // ---- main loop ----
    for (int kt = 0; kt < NT; ++kt) {
        const int p = kt & 1;
        #pragma unroll
        for (int q = 0; q < NPH; ++q) {
            if (q == 0) ldB(p);
            ldA(p, q);
            if (q == 0) {
                if (kt + 1 < NT) stageA(p ^ 1, kt + 1, NPH - 1);
            } else if (q == 1) {
                if (kt + 2 < NT) { stageB(p, kt + 2); stageA(p, kt + 2, 0); }
            } else {
                if (kt + 2 < NT) stageA(p, kt + 2, q - 1);
            }
            if (q == NPH - 1) {
                if (kt + 2 < NT) {
                    asm volatile("s_waitcnt vmcnt(%0)" :: "n"(NWT) : "memory");
                } else if (kt + 1 < NT) {
                    asm volatile("s_waitcnt vmcnt(0)" ::: "memory");
                }
            }
            __builtin_amdgcn_s_barrier();
            // pin all of this wave's ds_reads complete before the end
            // barrier (slot-reuse race-freedom) and keep MFMAs from
            // hoisting above it (rule #18).
            asm volatile("s_waitcnt lgkmcnt(0)" ::: "memory");
            __builtin_amdgcn_sched_barrier(0);
            __builtin_amdgcn_s_setprio(1);
            #pragma unroll
            for (int m2 = 0; m2 < 2; ++m2)
                #pragma unroll
                for (int n2 = 0; n2 < NI; ++n2)
                    #pragma unroll
                    for (int kk = 0; kk < 2; ++kk)
                        acc[q * 2 + m2][n2] = __builtin_amdgcn_mfma_f32_16x16x32_bf16(
                            af[m2][kk], bf[n2][kk], acc[q * 2 + m2][n2], 0, 0, 0);
            __builtin_amdgcn_s_setprio(0);
            __builtin_amdgcn_s_barrier();
        }
    }

    // ---- epilogues. C/D layout: col = l16, row = quad*4 + reg ----
    if constexpr (MODE == 3) {
        unsigned short* Pz = (unsigned short*)C + (size_t)zb * cZ;
        float* rs = rowsum + (size_t)zb * M;
        #pragma unroll
        for (int mi = 0; mi < MI; ++mi) {
            #pragma unroll
            for (int r = 0; r < 4; ++r) {
                const int row = mBase + wr * RW + mi * 16 + quad * 4 + r;
                float e[NI];
                float partial = 0.f;
                #pragma unroll
                for (int ni = 0; ni < NI; ++ni) {
                    e[ni] = __expf(acc[mi][ni][r] * alpha);
                    partial += e[ni];
                }
                #pragma unroll
                for (int ni = 0; ni < NI; ++ni) {
                    const int col = nBase + wc * CW + ni * 16 + l16;
                    Pz[(size_t)row * N + col] = f32_to_bf16_rne(e[ni]);
                }
                #pragma unroll
                for (int off = 1; off < 16; off <<= 1)
                    partial += __shfl_xor(partial, off, 64);
                if (l16 == 0) atomicAdd(&rs[row], partial);
            }
        }
    } else {  // MODE 6
        float* Cz = (float*)C + (size_t)zb * cZ;
        const float* rs = rowsum + (size_t)zb * M;
        #pragma unroll
        for (int mi = 0; mi < MI; ++mi) {
            #pragma unroll
            for (int r = 0; r < 4; ++r) {
                const int row = mBase + wr * RW + mi * 16 + quad * 4 + r;
                const float inv = 1.f / rs[row];
                #pragma unroll
                for (int ni = 0; ni < NI; ++ni) {
                    const int col = nBase + wc * CW + ni * 16 + l16;
                    Cz[(size_t)row * N + col] = acc[mi][ni][r] * inv + b0[col];
                }
            }
        }
    }
}

// ---------------------------------------------------------------------------
extern "C" void kernel_launch(void* const* d_in, const int* in_sizes, int n_in,
                              void* d_out, int out_size, void* d_ws, size_t ws_size,
                              hipStream_t stream)
{
    const float* x  = (const float*)d_in[0];
    const float* Wq = (const float*)d_in[1];
    const float* bq = (const float*)d_in[2];
    const float* Wk = (const float*)d_in[3];
    const float* Wv = (const float*)d_in[5];
    const float* bv = (const float*)d_in[6];
    const float* Wo = (const float*)d_in[7];
    const float* bo = (const float*)d_in[8];
    float* out = (float*)d_out;

    const int S = 4096, H = 1024, Bsz = 2;
    const int M = Bsz * S;   // 8192

    char* p = (char*)d_ws;
    auto alloc = [&](size_t bytes) -> char* {
        char* r = p; p += (bytes + 255) & ~(size_t)255; return r;
    };
    // footprint ~124 MiB (ws >= 153 MiB proven in R2)
    unsigned short* w16   = (unsigned short*)alloc((size_t)4 * H * H * 2);  // WqT|WkT|Wo|WvT
    unsigned short* F16   = (unsigned short*)alloc((size_t)H * H * 2);
    unsigned short* Gt16  = (unsigned short*)alloc((size_t)H * H * 2);
    unsigned short* qg16  = (unsigned short*)alloc((size_t)M * H * 2);
    unsigned short* vot16 = (unsigned short*)alloc((size_t)Bsz * H * S * 2); // [B][H][S]
    unsigned short* x16   = (unsigned short*)alloc((size_t)M * H * 2);
    float*          rsum  = (float*)alloc((size_t)M * 4);
    float*          bfin  = (float*)alloc((size_t)H * 4);
    float*          g0    = (float*)alloc((size_t)H * 4);
    unsigned short* p16   = (unsigned short*)alloc((size_t)Bsz * S * S * 2);

    // 1) converts + transposes + bfinal + rsum zeroing   (one dispatch)
    cvt_all<<<10008, 256, 0, stream>>>(x, Wq, Wk, Wo, Wv, bv, bo,
                                       x16, w16, rsum, bfin);

    // 2) Gt = WkT.WqT^T, F = Wo.WvT^T, g0 = bq^T Wk  (one dispatch)
    gemm_gf<<<144, 256, 0, stream>>>(w16, Gt16, F16, bq, g0);

    // 3) qg = x.Gt^T + g0  and  Vot[b] = F.x_b^T
    gemm_qgv<<<1024, 256, 0, stream>>>(x16, Gt16, F16, g0, qg16, vot16);

    // 4) P_un[b] = exp((qg.x_b^T)/8) + atomic rowsums  (256x256 phase-split,
    //    register-fix applied)
    gemm8p<3, 256, 256><<<512, 512, 0, stream>>>(
        qg16, x16, p16, nullptr, rsum, 0.125f, S, S, 1024,
        (long long)S * H, (long long)S * H, (long long)S * S, 16, 16);

    // 5) out[b] = (P_un . Vot^T)/rowsum + bfinal   (128x256 phase-split)
    gemm8p<6, 128, 256><<<256, 512, 0, stream>>>(
        p16, vot16, out, bfin, rsum, 1.f, S, H, 4096,
        (long long)S * S, (long long)H * S, (long long)S * H, 32, 4);
}

// Round 9
// 335.696 us; speedup vs baseline: 1.0257x; 1.0229x over previous
//
#include <hip/hip_runtime.h>
#include <stdint.h>

// ---------------------------------------------------------------------------
// DistributedAttention on MI355X (gfx950)
//   q = x Wq^T + bq ; k = x Wk^T + bk ; v = x Wv^T + bv
//   P = softmax(q k^T / 8) ; out = P v Wo^T + bo
// Factorizations:
//   F  = Wo . Wv                  (2.1 GF, replaces the 17.2 GF v-proj)  [R7]
//   Vot= F . x^T per batch        ([H][S] bf16)                          [R7]
//   G  = Wq^T . Wk  (batch-indep) ; qg = x . G + g0, g0 = bq^T Wk        [R11]
//   scores = qg . x^T   (row-constant terms cancel in softmax)           [R12]
//   P_un = exp(scores / 8)        (bf16 + atomic fp32 rowsums)
//   out  = (P_un . Vot^T)/rowsum + bfinal,  bfinal = bo + Wo.bv
// R17: recombination of measured-best variants.
//   R16 falsified the register-spill theory (VGPR_Count excludes AGPR acc;
//   256^2 8-phase = 114.7 µs a third time -> structural, retired for good).
//   BUT R16's totals leaked a win: scores +24.3 µs vs R15 while total was
//   -0.9 -> the __launch_bounds__(512,2) bound improved FINAL by ~25 µs
//   (default-occupancy VGPR budgeting was strangling the 128x256 instance).
//   So: scores = gemm_sc (128^2 2-barrier, 90.4 µs, proven 4x);
//       final  = gemm8p<128,256> WITH (512,2) bound (R16 config).
//   If total lands ~344 instead of ~320, the bound did nothing and R16's
//   total was noise -> A/B final's bound explicitly next round.
// ---------------------------------------------------------------------------

typedef __bf16 bf16x8 __attribute__((ext_vector_type(8)));
typedef float  f32x4  __attribute__((ext_vector_type(4)));

__device__ __forceinline__ unsigned short f32_to_bf16_rne(float f) {
    uint32_t u = __builtin_bit_cast(uint32_t, f);
    uint32_t r = (u + 0x7FFFu + ((u >> 16) & 1u)) >> 16;
    return (unsigned short)r;
}

#define BM 128
#define BN 128
#define BK 64

// ---------------------------------------------------------------------------
// One-dispatch prep, 10008 blocks:
//   [0,8192)        x fp32 -> x16 bf16
//   [8192,9216)     Wo straight convert -> w16 slot 2
//   [9216,9984)     WqT, WkT, WvT 64x64-tile transposes -> slots 0,1,3
//   [9984,10000)    bfinal = bo + Wo.bv
//   [10000,10008)   zero rsum
// ---------------------------------------------------------------------------
__global__ __launch_bounds__(256) void cvt_all(
    const float* __restrict__ x,
    const float* __restrict__ Wq, const float* __restrict__ Wk,
    const float* __restrict__ Wo, const float* __restrict__ Wv,
    const float* __restrict__ bv, const float* __restrict__ bo,
    unsigned short* __restrict__ x16, unsigned short* __restrict__ w16,
    float* __restrict__ rsum, float* __restrict__ bfinal)
{
    const int b = blockIdx.x, tid = threadIdx.x;
    if (b < 8192) {
        int i = (b * 256 + tid) * 4;
        float4 v = *(const float4*)(x + i);
        ushort4 o;
        o.x = f32_to_bf16_rne(v.x); o.y = f32_to_bf16_rne(v.y);
        o.z = f32_to_bf16_rne(v.z); o.w = f32_to_bf16_rne(v.w);
        *(ushort4*)(x16 + i) = o;
    } else if (b < 9216) {
        int i = ((b - 8192) * 256 + tid) * 4;
        float4 v = *(const float4*)(Wo + i);
        ushort4 o;
        o.x = f32_to_bf16_rne(v.x); o.y = f32_to_bf16_rne(v.y);
        o.z = f32_to_bf16_rne(v.z); o.w = f32_to_bf16_rne(v.w);
        *(ushort4*)(w16 + (size_t)2 * 1048576 + i) = o;
    } else if (b < 9984) {
        // transpose one 64x64 tile of {Wq,Wk,Wv} into w16 slot {0,1,3}
        __shared__ unsigned short tl[64 * 68];   // [c][r], stride 68
        int t = b - 9216;
        int which = t >> 8;                      // 0:Wq 1:Wk 2:Wv
        const float* src = which == 0 ? Wq : which == 1 ? Wk : Wv;
        size_t slot = which == 0 ? 0 : which == 1 ? 1 : 3;
        int tile = t & 255, tr = tile >> 4, tc = tile & 15;
        #pragma unroll
        for (int it = 0; it < 4; ++it) {
            int r  = it * 16 + (tid >> 4);
            int c0 = (tid & 15) * 4;
            float4 v = *(const float4*)(src + (size_t)(tr * 64 + r) * 1024 + tc * 64 + c0);
            tl[(c0 + 0) * 68 + r] = f32_to_bf16_rne(v.x);
            tl[(c0 + 1) * 68 + r] = f32_to_bf16_rne(v.y);
            tl[(c0 + 2) * 68 + r] = f32_to_bf16_rne(v.z);
            tl[(c0 + 3) * 68 + r] = f32_to_bf16_rne(v.w);
        }
        __syncthreads();
        #pragma unroll
        for (int it = 0; it < 4; ++it) {
            int c  = it * 16 + (tid >> 4);
            int r0 = (tid & 15) * 4;
            ushort4 o;
            o.x = tl[c * 68 + r0 + 0]; o.y = tl[c * 68 + r0 + 1];
            o.z = tl[c * 68 + r0 + 2]; o.w = tl[c * 68 + r0 + 3];
            *(ushort4*)(w16 + slot * 1048576 + (size_t)(tc * 64 + c) * 1024 + tr * 64 + r0) = o;
        }
    } else if (b < 10000) {
        // bfinal[row] = bo[row] + dot(Wo[row,:], bv)
        int bb = b - 9984;
        int lane = tid & 63, wv_ = tid >> 6;
        int rowBase = bb * 64 + wv_ * 16;
        for (int rr = 0; rr < 16; ++rr) {
            int row = rowBase + rr;
            float partial = 0.f;
            #pragma unroll
            for (int t2 = 0; t2 < 16; ++t2) {
                int h = t2 * 64 + lane;
                partial += Wo[(size_t)row * 1024 + h] * bv[h];
            }
            #pragma unroll
            for (int off = 32; off > 0; off >>= 1)
                partial += __shfl_xor(partial, off, 64);
            if (lane == 0) bfinal[row] = bo[row] + partial;
        }
    } else {
        int i = (b - 10000) * 1024 + tid * 4;
        *(float4*)(rsum + i) = float4{0.f, 0.f, 0.f, 0.f};
    }
}

// ---------------------------------------------------------------------------
// Proven 128^2 K-loop (R5 codegen) — gf, qgv, scores.
// ---------------------------------------------------------------------------
__device__ __forceinline__ void gemm_core(
    const unsigned short* __restrict__ Ab,
    const unsigned short* __restrict__ Bb,
    unsigned short* ldsA, unsigned short* ldsB,
    int mBase, int nBase, int lane, int wave, int K, f32x4 (&acc)[4][4])
{
    const int quad = lane >> 4;
    const int l16  = lane & 15;
    const int wr   = wave >> 1;
    const int wc   = wave & 1;

    for (int k0 = 0; k0 < K; k0 += BK) {
        #pragma unroll
        for (int i = 0; i < 4; ++i) {
            int base = (i * 4 + wave) * 64;
            int s    = base + lane;
            int row  = s >> 3;
            int col  = ((s ^ (s >> 3)) & 7) * 8;
            __builtin_amdgcn_global_load_lds(
                (const __attribute__((address_space(1))) void*)(Ab + (size_t)(mBase + row) * K + (size_t)(k0 + col)),
                (__attribute__((address_space(3))) void*)(&ldsA[base * 8]),
                16, 0, 0);
        }
        #pragma unroll
        for (int i = 0; i < 4; ++i) {
            int base = (i * 4 + wave) * 64;
            int s    = base + lane;
            int row  = s >> 3;
            int col  = ((s ^ (s >> 3)) & 7) * 8;
            __builtin_amdgcn_global_load_lds(
                (const __attribute__((address_space(1))) void*)(Bb + (size_t)(nBase + row) * K + (size_t)(k0 + col)),
                (__attribute__((address_space(3))) void*)(&ldsB[base * 8]),
                16, 0, 0);
        }
        __syncthreads();

        #pragma unroll
        for (int kk = 0; kk < 2; ++kk) {
            bf16x8 af[4], bfv[4];
            #pragma unroll
            for (int mi = 0; mi < 4; ++mi) {
                int r = wr * 64 + mi * 16 + l16;
                int c = kk * 4 + quad;
                af[mi] = *(const bf16x8*)(&ldsA[r * BK + (((c ^ r) & 7) << 3)]);
            }
            #pragma unroll
            for (int ni = 0; ni < 4; ++ni) {
                int r = wc * 64 + ni * 16 + l16;
                int c = kk * 4 + quad;
                bfv[ni] = *(const bf16x8*)(&ldsB[r * BK + (((c ^ r) & 7) << 3)]);
            }
            #pragma unroll
            for (int mi = 0; mi < 4; ++mi)
                #pragma unroll
                for (int ni = 0; ni < 4; ++ni)
                    acc[mi][ni] = __builtin_amdgcn_mfma_f32_16x16x32_bf16(
                        af[mi], bfv[ni], acc[mi][ni], 0, 0, 0);
        }
        __syncthreads();
    }
}

// ---------------------------------------------------------------------------
// Small dispatch (144 blocks):
//   [0,64)    Gt = WkT.(WqT)^T
//   [64,128)  F  = Wo.(WvT)^T
//   [128,144) g0[j] = dot(bq, WkT row j)  (coalesced bf16x8 row reads)
// ---------------------------------------------------------------------------
__global__ __launch_bounds__(256) void gemm_gf(
    const unsigned short* __restrict__ w16,
    unsigned short* __restrict__ Gt16, unsigned short* __restrict__ F16,
    const float* __restrict__ bq, float* __restrict__ g0)
{
    const int l = blockIdx.x, tid = threadIdx.x;
    if (l < 128) {
        __shared__ unsigned short ldsA[BM * BK];
        __shared__ unsigned short ldsB[BN * BK];
        const unsigned short *Ab, *Bb;
        unsigned short* Cb;
        int f;
        if (l < 64) { f = l;      Ab = w16 + (size_t)1 * 1048576; Bb = w16;                        Cb = Gt16; }
        else        { f = l - 64; Ab = w16 + (size_t)2 * 1048576; Bb = w16 + (size_t)3 * 1048576; Cb = F16;  }
        int mBase = (f >> 3) * BM, nBase = (f & 7) * BN;

        const int lane = tid & 63, wave = tid >> 6;
        const int quad = lane >> 4, l16 = lane & 15;
        const int wr = wave >> 1, wc = wave & 1;

        f32x4 acc[4][4] = {};
        gemm_core(Ab, Bb, ldsA, ldsB, mBase, nBase, lane, wave, 1024, acc);

        #pragma unroll
        for (int mi = 0; mi < 4; ++mi)
            #pragma unroll
            for (int ni = 0; ni < 4; ++ni) {
                int col = nBase + wc * 64 + ni * 16 + l16;
                #pragma unroll
                for (int r = 0; r < 4; ++r) {
                    int row = mBase + wr * 64 + mi * 16 + quad * 4 + r;
                    Cb[(size_t)row * 1024 + col] = f32_to_bf16_rne(acc[mi][ni][r]);
                }
            }
    } else {
        // g0 rows: 16 blocks x 4 waves x 16 rows = 1024
        int rb = l - 128;
        int lane = tid & 63, w = tid >> 6;
        const unsigned short* WkT = w16 + (size_t)1 * 1048576;
        float bq0[8], bq1[8];
        #pragma unroll
        for (int i = 0; i < 8; ++i) {
            bq0[i] = bq[lane * 8 + i];
            bq1[i] = bq[512 + lane * 8 + i];
        }
        for (int rr = 0; rr < 16; ++rr) {
            int j = (rb * 4 + w) * 16 + rr;
            bf16x8 a0 = *(const bf16x8*)(WkT + (size_t)j * 1024 + lane * 8);
            bf16x8 a1 = *(const bf16x8*)(WkT + (size_t)j * 1024 + 512 + lane * 8);
            float partial = 0.f;
            #pragma unroll
            for (int i = 0; i < 8; ++i)
                partial += bq0[i] * (float)a0[i] + bq1[i] * (float)a1[i];
            #pragma unroll
            for (int off = 32; off > 0; off >>= 1)
                partial += __shfl_xor(partial, off, 64);
            if (lane == 0) g0[j] = partial;
        }
    }
}

// ---------------------------------------------------------------------------
// qg = x.Gt^T + g0 (512 tiles) and Vot[b] = F.x_b^T (512 tiles), merged.
// 1024 blocks, XCD-contiguous.
// ---------------------------------------------------------------------------
__global__ __launch_bounds__(256) void gemm_qgv(
    const unsigned short* __restrict__ x16,
    const unsigned short* __restrict__ Gt16,
    const unsigned short* __restrict__ F16,
    const float* __restrict__ g0,
    unsigned short* __restrict__ qg16,
    unsigned short* __restrict__ vot16)
{
    __shared__ unsigned short ldsA[BM * BK];
    __shared__ unsigned short ldsB[BN * BK];

    int l   = blockIdx.x;                 // 1024 = 8 * 128
    int idx = (l & 7) * 128 + (l >> 3);   // XCD-contiguous

    const unsigned short *Ab, *Bb;
    unsigned short* Cb;
    const float* bias;
    int mBase, nBase, Cstride;
    if (idx < 512) {
        // qg: M=8192 (both batches), N=1024, K=1024
        mBase = (idx >> 3) * BM; nBase = (idx & 7) * BN;
        Ab = x16; Bb = Gt16; Cb = qg16; bias = g0; Cstride = 1024;
    } else {
        // Vot[b]: M=1024, N=4096, K=1024
        int v = idx - 512;
        int zb = v >> 8, t2 = v & 255;
        mBase = (t2 >> 5) * BM; nBase = (t2 & 31) * BN;
        Ab = F16; Bb = x16 + (size_t)zb * 4096 * 1024;
        Cb = vot16 + (size_t)zb * 1024 * 4096; bias = nullptr; Cstride = 4096;
    }

    const int tid  = threadIdx.x;
    const int lane = tid & 63;
    const int wave = tid >> 6;
    const int quad = lane >> 4;
    const int l16  = lane & 15;
    const int wr   = wave >> 1;
    const int wc   = wave & 1;

    f32x4 acc[4][4] = {};
    gemm_core(Ab, Bb, ldsA, ldsB, mBase, nBase, lane, wave, 1024, acc);

    #pragma unroll
    for (int mi = 0; mi < 4; ++mi)
        #pragma unroll
        for (int ni = 0; ni < 4; ++ni) {
            int col = nBase + wc * 64 + ni * 16 + l16;
            float b = bias ? bias[col] : 0.f;
            #pragma unroll
            for (int r = 0; r < 4; ++r) {
                int row = mBase + wr * 64 + mi * 16 + quad * 4 + r;
                Cb[(size_t)row * Cstride + col] = f32_to_bf16_rne(acc[mi][ni][r] + b);
            }
        }
}

// ---------------------------------------------------------------------------
// scores: z-batched A.Bt^T, 128^2 proven path (90.4 µs, proven 4x).
// C bf16 = exp(acc * alpha), atomic fp32 rowsums.
// ---------------------------------------------------------------------------
__global__ __launch_bounds__(256) void gemm_sc(
    const unsigned short* __restrict__ A,
    const unsigned short* __restrict__ Bt,
    unsigned short* __restrict__ C,
    float* __restrict__ rowsum,
    float alpha, int M, int N, int K,
    long long aZ, long long bZ, long long cZ)
{
    __shared__ unsigned short ldsA[BM * BK];
    __shared__ unsigned short ldsB[BN * BK];

    const int NB = gridDim.x, MBt = gridDim.y;
    int l  = blockIdx.x + gridDim.x * (blockIdx.y + gridDim.y * blockIdx.z);
    int xcd = l & 7;
    int t   = l >> 3;
    int MBX = MBt >> 1;
    int NBX = NB >> 2;
    int mbl = t % MBX;
    int r1  = t / MBX;
    int nbi = r1 % NBX;
    int zb  = r1 / NBX;
    int mb  = (xcd >> 2) * MBX + mbl;
    int nb  = (xcd & 3) * NBX + nbi;

    const unsigned short* Ab = A  + (size_t)zb * aZ;
    const unsigned short* Bb = Bt + (size_t)zb * bZ;

    const int tid  = threadIdx.x;
    const int lane = tid & 63;
    const int wave = tid >> 6;
    const int quad = lane >> 4;
    const int l16  = lane & 15;
    const int wr   = wave >> 1;
    const int wc   = wave & 1;
    const int mBase = mb * BM;
    const int nBase = nb * BN;

    f32x4 acc[4][4] = {};
    gemm_core(Ab, Bb, ldsA, ldsB, mBase, nBase, lane, wave, K, acc);

    unsigned short* Pz = C + (size_t)zb * cZ;
    float* rs = rowsum + (size_t)zb * M;
    #pragma unroll
    for (int mi = 0; mi < 4; ++mi) {
        #pragma unroll
        for (int r = 0; r < 4; ++r) {
            int row = mBase + wr * 64 + mi * 16 + quad * 4 + r;
            float e[4];
            float partial = 0.f;
            #pragma unroll
            for (int ni = 0; ni < 4; ++ni) {
                e[ni] = __expf(acc[mi][ni][r] * alpha);
                partial += e[ni];
            }
            #pragma unroll
            for (int ni = 0; ni < 4; ++ni) {
                int col = nBase + wc * 64 + ni * 16 + l16;
                Pz[(size_t)row * N + col] = f32_to_bf16_rne(e[ni]);
            }
            #pragma unroll
            for (int off = 1; off < 16; off <<= 1)
                partial += __shfl_xor(partial, off, 64);
            if (l16 == 0) atomicAdd(&rs[row], partial);
        }
    }
}

// ---------------------------------------------------------------------------
// final: phase-split GEMM (R10-corrected m201 schedule), 128x256, K=4096,
// with the R16 occupancy bound __launch_bounds__(512, 2) — this bound is the
// measured ~25 µs win on this instance (R15->R16 totals with scores held
// accountable). 8 waves (2m x 4n), BK=64, double-buffered xor-swizzled LDS,
// global_load_lds(16B), counted vmcnt once per K-tile. Phase = {ds_read
// subtile + stage issue + [vmcnt] -> s_barrier -> lgkmcnt(0)+
// sched_barrier(0) -> setprio(1) 16xMFMA setprio(0) -> s_barrier}.
// C fp32 = acc/rowsum + b0.
// ---------------------------------------------------------------------------
template <int BMt, int BNt>
__global__ __launch_bounds__(512, 2) void gemm8p(
    const unsigned short* __restrict__ A,
    const unsigned short* __restrict__ Bt,
    float* __restrict__ C,
    const float* __restrict__ b0, const float* __restrict__ rowsum,
    int M, int N, int K,
    long long aZ, long long bZ, long long cZ,
    int MBt, int NB)
{
    constexpr int RW  = BMt / 2;           // rows per wave
    constexpr int CW  = BNt / 4;           // cols per wave (= 64)
    constexpr int MI  = RW / 16;           // m-frags per wave
    constexpr int NI  = CW / 16;           // n-frags per wave (= 4)
    constexpr int NPH = MI / 2;            // phases per K-tile
    constexpr int BL  = (BNt * 64 / 512) / 8;  // B loads/wave/K-tile (= 4)
    constexpr int NWT = BL + NPH - 1;      // steady-state counted vmcnt

    __shared__ __align__(16) unsigned short ldsA[2][BMt * 64];
    __shared__ __align__(16) unsigned short ldsB[2][BNt * 64];

    const int l   = blockIdx.x;
    const int xcd = l & 7;
    const int t   = l >> 3;
    const int MBX = MBt >> 1;
    const int NBX = NB >> 2;
    const int mbl = t % MBX;
    const int r1  = t / MBX;
    const int nbi = r1 % NBX;
    const int zb  = r1 / NBX;
    const int mb  = (xcd >> 2) * MBX + mbl;
    const int nb  = (xcd & 3) * NBX + nbi;

    const unsigned short* Ab = A  + (size_t)zb * aZ;
    const unsigned short* Bb = Bt + (size_t)zb * bZ;

    const int tid  = threadIdx.x;
    const int lane = tid & 63;
    const int wave = tid >> 6;
    const int quad = lane >> 4;
    const int l16  = lane & 15;
    const int wr   = wave >> 2;            // 0..1
    const int wc   = wave & 3;             // 0..3
    const int mBase = mb * BMt;
    const int nBase = nb * BNt;
    const int NT    = K >> 6;

    // each wave stages one 8-row octet per A-strip-half and BL octets of B
    const int aRow0 = ((wave & 4) ? RW : 0) + (wave & 3) * 8;

    auto stageA = [&](int p, int kt, int q) {
        const int rowbase = aRow0 + q * 32;
        const int row = rowbase + (lane >> 3);
        const int col = (((lane & 7) ^ row) & 7) << 3;   // pre-swizzled source
        __builtin_amdgcn_global_load_lds(
            (const __attribute__((address_space(1))) void*)(
                Ab + (size_t)(mBase + row) * K + (size_t)((kt << 6) + col)),
            (__attribute__((address_space(3))) void*)(&ldsA[p][rowbase * 64]),
            16, 0, 0);
    };
    auto stageB = [&](int p, int kt) {
        #pragma unroll
        for (int i = 0; i < BL; ++i) {
            const int g   = wave * BL + i;
            const int row = (g << 3) + (lane >> 3);
            const int col = (((lane & 7) ^ row) & 7) << 3;
            __builtin_amdgcn_global_load_lds(
                (const __attribute__((address_space(1))) void*)(
                    Bb + (size_t)(nBase + row) * K + (size_t)((kt << 6) + col)),
                (__attribute__((address_space(3))) void*)(&ldsB[p][g << 9]),
                16, 0, 0);
        }
    };

    bf16x8 bf[NI][2];
    bf16x8 af[2][2];
    auto ldB = [&](int p) {
        #pragma unroll
        for (int n2 = 0; n2 < NI; ++n2)
            #pragma unroll
            for (int kk = 0; kk < 2; ++kk) {
                const int r = wc * CW + n2 * 16 + l16;
                const int c = kk * 4 + quad;
                bf[n2][kk] = *(const bf16x8*)&ldsB[p][r * 64 + (((c ^ r) & 7) << 3)];
            }
    };
    auto ldA = [&](int p, int q) {
        #pragma unroll
        for (int m2 = 0; m2 < 2; ++m2)
            #pragma unroll
            for (int kk = 0; kk < 2; ++kk) {
                const int r = wr * RW + (q * 2 + m2) * 16 + l16;
                const int c = kk * 4 + quad;
                af[m2][kk] = *(const bf16x8*)&ldsA[p][r * 64 + (((c ^ r) & 7) << 3)];
            }
    };

    f32x4 acc[MI][NI] = {};

    // ---- prologue: tile0 fully + tile1 all but its last strip ----
    stageB(0, 0);
    #pragma unroll
    for (int q = 0; q < NPH; ++q) stageA(0, 0, q);
    if (NT > 1) {
        stageB(1, 1);
        #pragma unroll
        for (int q = 0; q < NPH - 1; ++q) stageA(1, 1, q);
        asm volatile("s_waitcnt vmcnt(%0)" :: "n"(NWT) : "memory");
    } else {
        asm volatile("s_waitcnt vmcnt(0)" ::: "memory");
    }
    __builtin_amdgcn_s_barrier();

    // ---- main loop ----
    for (int kt = 0; kt < NT; ++kt) {
        const int p = kt & 1;
        #pragma unroll
        for (int q = 0; q < NPH; ++q) {
            if (q == 0) ldB(p);
            ldA(p, q);
            if (q == 0) {
                if (kt + 1 < NT) stageA(p ^ 1, kt + 1, NPH - 1);
            } else if (q == 1) {
                if (kt + 2 < NT) { stageB(p, kt + 2); stageA(p, kt + 2, 0); }
            } else {
                if (kt + 2 < NT) stageA(p, kt + 2, q - 1);
            }
            if (q == NPH - 1) {
                if (kt + 2 < NT) {
                    asm volatile("s_waitcnt vmcnt(%0)" :: "n"(NWT) : "memory");
                } else if (kt + 1 < NT) {
                    asm volatile("s_waitcnt vmcnt(0)" ::: "memory");
                }
            }
            __builtin_amdgcn_s_barrier();
            // pin all of this wave's ds_reads complete before the end
            // barrier (slot-reuse race-freedom) and keep MFMAs from
            // hoisting above it (rule #18).
            asm volatile("s_waitcnt lgkmcnt(0)" ::: "memory");
            __builtin_amdgcn_sched_barrier(0);
            __builtin_amdgcn_s_setprio(1);
            #pragma unroll
            for (int m2 = 0; m2 < 2; ++m2)
                #pragma unroll
                for (int n2 = 0; n2 < NI; ++n2)
                    #pragma unroll
                    for (int kk = 0; kk < 2; ++kk)
                        acc[q * 2 + m2][n2] = __builtin_amdgcn_mfma_f32_16x16x32_bf16(
                            af[m2][kk], bf[n2][kk], acc[q * 2 + m2][n2], 0, 0, 0);
            __builtin_amdgcn_s_setprio(0);
            __builtin_amdgcn_s_barrier();
        }
    }

    // ---- epilogue. C/D layout: col = l16, row = quad*4 + reg ----
    {
        float* Cz = C + (size_t)zb * cZ;
        const float* rs = rowsum + (size_t)zb * M;
        #pragma unroll
        for (int mi = 0; mi < MI; ++mi) {
            #pragma unroll
            for (int r = 0; r < 4; ++r) {
                const int row = mBase + wr * RW + mi * 16 + quad * 4 + r;
                const float inv = 1.f / rs[row];
                #pragma unroll
                for (int ni = 0; ni < NI; ++ni) {
                    const int col = nBase + wc * CW + ni * 16 + l16;
                    Cz[(size_t)row * N + col] = acc[mi][ni][r] * inv + b0[col];
                }
            }
        }
    }
}

// ---------------------------------------------------------------------------
extern "C" void kernel_launch(void* const* d_in, const int* in_sizes, int n_in,
                              void* d_out, int out_size, void* d_ws, size_t ws_size,
                              hipStream_t stream)
{
    const float* x  = (const float*)d_in[0];
    const float* Wq = (const float*)d_in[1];
    const float* bq = (const float*)d_in[2];
    const float* Wk = (const float*)d_in[3];
    const float* Wv = (const float*)d_in[5];
    const float* bv = (const float*)d_in[6];
    const float* Wo = (const float*)d_in[7];
    const float* bo = (const float*)d_in[8];
    float* out = (float*)d_out;

    const int S = 4096, H = 1024, Bsz = 2;
    const int M = Bsz * S;   // 8192

    char* p = (char*)d_ws;
    auto alloc = [&](size_t bytes) -> char* {
        char* r = p; p += (bytes + 255) & ~(size_t)255; return r;
    };
    // footprint ~124 MiB (ws >= 153 MiB proven in R2)
    unsigned short* w16   = (unsigned short*)alloc((size_t)4 * H * H * 2);  // WqT|WkT|Wo|WvT
    unsigned short* F16   = (unsigned short*)alloc((size_t)H * H * 2);
    unsigned short* Gt16  = (unsigned short*)alloc((size_t)H * H * 2);
    unsigned short* qg16  = (unsigned short*)alloc((size_t)M * H * 2);
    unsigned short* vot16 = (unsigned short*)alloc((size_t)Bsz * H * S * 2); // [B][H][S]
    unsigned short* x16   = (unsigned short*)alloc((size_t)M * H * 2);
    float*          rsum  = (float*)alloc((size_t)M * 4);
    float*          bfin  = (float*)alloc((size_t)H * 4);
    float*          g0    = (float*)alloc((size_t)H * 4);
    unsigned short* p16   = (unsigned short*)alloc((size_t)Bsz * S * S * 2);

    // 1) converts + transposes + bfinal + rsum zeroing   (one dispatch)
    cvt_all<<<10008, 256, 0, stream>>>(x, Wq, Wk, Wo, Wv, bv, bo,
                                       x16, w16, rsum, bfin);

    // 2) Gt = WkT.WqT^T, F = Wo.WvT^T, g0 = bq^T Wk  (one dispatch)
    gemm_gf<<<144, 256, 0, stream>>>(w16, Gt16, F16, bq, g0);

    // 3) qg = x.Gt^T + g0  and  Vot[b] = F.x_b^T
    gemm_qgv<<<1024, 256, 0, stream>>>(x16, Gt16, F16, g0, qg16, vot16);

    // 4) P_un[b] = exp((qg.x_b^T)/8) + atomic rowsums  (128^2 proven path)
    gemm_sc<<<dim3(S / BN, S / BM, 2), 256, 0, stream>>>(
        qg16, x16, p16, rsum, 0.125f, S, S, 1024,
        (long long)S * H, (long long)S * H, (long long)S * S);

    // 5) out[b] = (P_un . Vot^T)/rowsum + bfinal  (128x256 phase-split, (512,2))
    gemm8p<128, 256><<<256, 512, 0, stream>>>(
        p16, vot16, out, bfin, rsum, S, H, 4096,
        (long long)S * S, (long long)H * S, (long long)S * H, 32, 4);
}